// Round 7
// baseline (143.627 us; speedup 1.0000x reference)
//
#include <hip/hip_runtime.h>
#include <hip/hip_bf16.h>

// PosteriorRotationN: B=8,T=120,N=24,D=48,C=1128,DE=256
// MEASUREMENT ROUND: k2 launched twice (idempotent) -> dur_us - 97.6 = k2 cost.
// k1 reverted to best-measured variant (R4: swapped operands, bn-grid).

constexpr int Bc = 8, Tc = 120, Nc = 24, Dc = 48, Cc = 1128, DEc = 256;
constexpr int BNc = Bc * Nc;        // 192
constexpr int KVP = 64;             // kv row padded to 64 (zeros at 48..63)

using short8 = __attribute__((ext_vector_type(8))) short;
using f32x4  = __attribute__((ext_vector_type(4))) float;

__device__ __forceinline__ ushort f2b(float f) {
    union { float f; unsigned u; } v; v.f = f;
    unsigned r = (v.u + 0x7fffu + ((v.u >> 16) & 1u)) >> 16;
    return (ushort)r;
}
__device__ __forceinline__ short bcast(float f) {
    return (short)__bfloat16_as_ushort(__float2bfloat16(f));
}
__device__ __forceinline__ short8 pack8(const float4& a, const float4& b) {
    short8 r;
    r[0] = bcast(a.x); r[1] = bcast(a.y); r[2] = bcast(a.z); r[3] = bcast(a.w);
    r[4] = bcast(b.x); r[5] = bcast(b.y); r[6] = bcast(b.z); r[7] = bcast(b.w);
    return r;
}

// ---------------- K0w: Wkv f32 -> bf16 ----------------
__global__ void k0w(const float* __restrict__ Wkv, ushort* __restrict__ wkvb) {
    int i = blockIdx.x * 256 + threadIdx.x;          // 3072 threads, 4 elems each
    float4 w = *reinterpret_cast<const float4*>(Wkv + i * 4);
    ushort4 u;
    u.x = (ushort)bcast(w.x); u.y = (ushort)bcast(w.y);
    u.z = (ushort)bcast(w.z); u.w = (ushort)bcast(w.w);
    *reinterpret_cast<ushort4*>(wkvb + i * 4) = u;
}

// ---------------- K1: kv GEMM, bf16 MFMA, swapped operands (R4 variant, 97.6) ----------------
constexpr int SWs = 264;  // Wkv LDS stride (bf16 elems): 528 B row
__global__ __launch_bounds__(256) void k1_kv(const float* __restrict__ ctx,
                                             const ushort* __restrict__ wkvb,
                                             const float* __restrict__ bkv,
                                             ushort* __restrict__ kvb) {
    __shared__ ushort sW[Dc * SWs];          // 25344 B, full K=256 of Wkv (bf16)
    const int bn = blockIdx.x, c0 = blockIdx.y * 128;
    const int b = bn / Nc, n = bn % Nc;
    const int tid = threadIdx.x, wave = tid >> 6, lane = tid & 63;
    const int tr = lane & 15, kg = lane >> 4;
    const float* ctxb = ctx + ((size_t)b * Cc * Nc + n) * DEc;

    for (int l = tid; l < Dc * 32; l += 256) {
        int d = l >> 5, e = (l & 31) << 3;
        *reinterpret_cast<short8*>(&sW[d * SWs + e]) =
            *reinterpret_cast<const short8*>(&wkvb[d * DEc + e]);
    }

    const float* crow[2];
    #pragma unroll
    for (int cn = 0; cn < 2; ++cn) {
        int c = c0 + wave * 32 + cn * 16 + tr;
        crow[cn] = ctxb + (size_t)(c < Cc ? c : Cc - 1) * (Nc * DEc);
    }

    f32x4 acc[3][2];
    #pragma unroll
    for (int mf = 0; mf < 3; ++mf)
        #pragma unroll
        for (int cn = 0; cn < 2; ++cn) acc[mf][cn] = (f32x4){0.f, 0.f, 0.f, 0.f};

    __syncthreads();

    #pragma unroll
    for (int ks = 0; ks < 8; ++ks) {           // K=256 in 8 steps of 32, no barriers
        const int e0 = ks * 32 + kg * 8;
        short8 bfrag[2];
        #pragma unroll
        for (int cn = 0; cn < 2; ++cn) {
            float4 a0 = *reinterpret_cast<const float4*>(crow[cn] + e0);
            float4 a1 = *reinterpret_cast<const float4*>(crow[cn] + e0 + 4);
            bfrag[cn] = pack8(a0, a1);
        }
        short8 afrag[3];
        #pragma unroll
        for (int mf = 0; mf < 3; ++mf)
            afrag[mf] = *reinterpret_cast<const short8*>(&sW[(mf * 16 + tr) * SWs + e0]);
        #pragma unroll
        for (int mf = 0; mf < 3; ++mf)
            #pragma unroll
            for (int cn = 0; cn < 2; ++cn)
                acc[mf][cn] = __builtin_amdgcn_mfma_f32_16x16x32_bf16(afrag[mf], bfrag[cn], acc[mf][cn], 0, 0, 0);
    }

    float4 bias[3];
    #pragma unroll
    for (int mf = 0; mf < 3; ++mf)
        bias[mf] = *reinterpret_cast<const float4*>(bkv + mf * 16 + kg * 4);
    #pragma unroll
    for (int cn = 0; cn < 2; ++cn) {
        int c = c0 + wave * 32 + cn * 16 + tr;
        if (c < Cc) {
            ushort* dst = kvb + ((size_t)bn * Cc + c) * KVP;
            #pragma unroll
            for (int mf = 0; mf < 3; ++mf) {
                ushort4 u;
                u.x = f2b(acc[mf][cn][0] + bias[mf].x);
                u.y = f2b(acc[mf][cn][1] + bias[mf].y);
                u.z = f2b(acc[mf][cn][2] + bias[mf].z);
                u.w = f2b(acc[mf][cn][3] + bias[mf].w);
                *reinterpret_cast<ushort4*>(dst + mf * 16 + kg * 4) = u;
            }
        }
    }
    {   // zero pad cols 48..63
        int row = lane >> 1, half = lane & 1;
        int c = c0 + wave * 32 + row;
        if (c < Cc) {
            short8 z = (short8){0, 0, 0, 0, 0, 0, 0, 0};
            *reinterpret_cast<short8*>(&kvb[((size_t)bn * Cc + c) * KVP + 48 + half * 8]) = z;
        }
    }
}

// ---------------- K2: sp MFMA + tanh + gather matvec (unchanged) ----------------
constexpr int SGs = 1136;  // sG f32 stride
__global__ __launch_bounds__(256) void k2_fused(const float* __restrict__ x,
                                                const ushort* __restrict__ kvb,
                                                float* __restrict__ out) {
    __shared__ float  sG[16 * SGs];    // 72704 B
    __shared__ float  sXf[16 * 52];    // 3328 B
    __shared__ ushort sXb[16 * 72];    // 2304 B (K-padded to 64 w/ zeros)
    const int L = blockIdx.x;
    const int bn = (L & 7) + 8 * (L >> 6);   // bn%8 == XCD slot
    const int tt = (L >> 3) & 7;
    const int b = bn / Nc, n = bn % Nc, t0 = tt * 16;
    const int tid = threadIdx.x, wave = tid >> 6, lane = tid & 63;
    const int tr = lane & 15, kg = lane >> 4;

    for (int l = tid; l < 16 * 72 / 4; l += 256)
        *reinterpret_cast<ushort4*>(&sXb[l * 4]) = make_ushort4(0, 0, 0, 0);
    __syncthreads();
    if (tid < 192) {
        int t = tid / 12, dv = (tid % 12) * 4, tg = t0 + t;
        float4 v = make_float4(0.f, 0.f, 0.f, 0.f);
        if (tg < Tc) v = *reinterpret_cast<const float4*>(x + (((size_t)b * Tc + tg) * Nc + n) * Dc + dv);
        *reinterpret_cast<float4*>(&sXf[t * 52 + dv]) = v;
        *reinterpret_cast<ushort4*>(&sXb[t * 72 + dv]) = make_ushort4(f2b(v.x), f2b(v.y), f2b(v.z), f2b(v.w));
    }
    __syncthreads();
    const short8 af0 = *reinterpret_cast<const short8*>(&sXb[tr * 72 + kg * 8]);
    const short8 af1 = *reinterpret_cast<const short8*>(&sXb[tr * 72 + 32 + kg * 8]);
    const ushort* kvbn = kvb + (size_t)bn * Cc * KVP;
    for (int nf = wave; nf < 71; nf += 4) {
        int c = nf * 16 + tr;
        int ce = c < Cc ? c : Cc - 1;
        short8 b0 = *reinterpret_cast<const short8*>(&kvbn[(size_t)ce * KVP + kg * 8]);
        short8 b1 = *reinterpret_cast<const short8*>(&kvbn[(size_t)ce * KVP + 32 + kg * 8]);
        f32x4 a = (f32x4){0.f, 0.f, 0.f, 0.f};
        a = __builtin_amdgcn_mfma_f32_16x16x32_bf16(af0, b0, a, 0, 0, 0);
        a = __builtin_amdgcn_mfma_f32_16x16x32_bf16(af1, b1, a, 0, 0, 0);
        #pragma unroll
        for (int r = 0; r < 4; ++r) {
            float g = 0.1f - 0.2f * __builtin_amdgcn_rcpf(__expf(2.0f * a[r]) + 1.0f);
            sG[(kg * 4 + r) * SGs + c] = g;
        }
    }
    __syncthreads();
    int ea[3], ta[3], tea[3];
    float dxa[3];
    #pragma unroll
    for (int p = 0; p < 3; ++p) {
        int idx = tid + p * 256;
        ta[p] = idx / 48; ea[p] = idx % 48;
        tea[p] = ea[p] * (ea[p] - 1) / 2;
        dxa[p] = 0.f;
    }
    int td = 0;
    #pragma unroll 4
    for (int d = 0; d < 48; ++d) {
        #pragma unroll
        for (int p = 0; p < 3; ++p) {
            bool gt = d > ea[p];
            int c = gt ? (td + ea[p]) : (tea[p] + d);
            float gv = sG[ta[p] * SGs + c];
            float xv = sXf[ta[p] * 52 + d];
            float m = gt ? xv : -xv;
            if (d == ea[p]) m = 0.f;
            dxa[p] = fmaf(m, gv, dxa[p]);
        }
        td += d;
    }
    #pragma unroll
    for (int p = 0; p < 3; ++p) {
        int tg = t0 + ta[p];
        if (tg < Tc)
            out[(((size_t)b * Tc + tg) * Nc + n) * Dc + ea[p]] = sXf[ta[p] * 52 + ea[p]] + dxa[p];
    }
}

extern "C" void kernel_launch(void* const* d_in, const int* in_sizes, int n_in,
                              void* d_out, int out_size, void* d_ws, size_t ws_size,
                              hipStream_t stream) {
    (void)in_sizes; (void)n_in; (void)out_size; (void)ws_size;
    const float* x   = (const float*)d_in[0];
    const float* ctx = (const float*)d_in[1];
    const float* Wkv = (const float*)d_in[2];
    const float* bkv = (const float*)d_in[3];
    float* out   = (float*)d_out;
    ushort* wkvb = (ushort*)d_ws;                          // 48*256*2 = 24 KB
    ushort* kvb  = (ushort*)((char*)d_ws + 32768);         // 192*1128*64*2 = 27.7 MB

    k0w<<<dim3(12), dim3(256), 0, stream>>>(Wkv, wkvb);
    k1_kv<<<dim3(BNc, 9), dim3(256), 0, stream>>>(ctx, wkvb, bkv, kvb);
    k2_fused<<<dim3(BNc * 8), dim3(256), 0, stream>>>(x, kvb, out);
    k2_fused<<<dim3(BNc * 8), dim3(256), 0, stream>>>(x, kvb, out);  // measurement: dur - 97.6 = k2
}

// Round 8
// 123.346 us; speedup vs baseline: 1.1644x; 1.1644x over previous
//
#include <hip/hip_runtime.h>
#include <hip/hip_bf16.h>

// PosteriorRotationN: B=8,T=120,N=24,D=48,C=1128,DE=256
// k0w: Wkv f32 -> bf16 (24 KB, L2-resident)
// k1 : kv GEMM (bf16 MFMA, swapped operands, bn-grid) -> kvb[bn][c][64]
// k2 : per (bn, 8-t tile): sp MFMA -> g=0.1*tanh(sp) scattered into dense skew rows
//      M[t][e][d] (bf16, LDS) -> phase B dense dot dx[t,e] = x[t,:]·M[t][e][:]

constexpr int Bc = 8, Tc = 120, Nc = 24, Dc = 48, Cc = 1128, DEc = 256;
constexpr int BNc = Bc * Nc;        // 192
constexpr int KVP = 64;             // kv row padded to 64 (zeros at 48..63)

using short8 = __attribute__((ext_vector_type(8))) short;
using f32x4  = __attribute__((ext_vector_type(4))) float;

__device__ __forceinline__ ushort f2b(float f) {
    union { float f; unsigned u; } v; v.f = f;
    unsigned r = (v.u + 0x7fffu + ((v.u >> 16) & 1u)) >> 16;
    return (ushort)r;
}
__device__ __forceinline__ short bcast(float f) {
    return (short)__bfloat16_as_ushort(__float2bfloat16(f));
}
__device__ __forceinline__ short8 pack8(const float4& a, const float4& b) {
    short8 r;
    r[0] = bcast(a.x); r[1] = bcast(a.y); r[2] = bcast(a.z); r[3] = bcast(a.w);
    r[4] = bcast(b.x); r[5] = bcast(b.y); r[6] = bcast(b.z); r[7] = bcast(b.w);
    return r;
}

// ---------------- K0w: Wkv f32 -> bf16 ----------------
__global__ void k0w(const float* __restrict__ Wkv, ushort* __restrict__ wkvb) {
    int i = blockIdx.x * 256 + threadIdx.x;
    float4 w = *reinterpret_cast<const float4*>(Wkv + i * 4);
    ushort4 u;
    u.x = (ushort)bcast(w.x); u.y = (ushort)bcast(w.y);
    u.z = (ushort)bcast(w.z); u.w = (ushort)bcast(w.w);
    *reinterpret_cast<ushort4*>(wkvb + i * 4) = u;
}

// ---------------- K1: kv GEMM, bf16 MFMA, swapped operands (best-measured) ----------------
constexpr int SWs = 264;  // Wkv LDS stride (bf16 elems)
__global__ __launch_bounds__(256) void k1_kv(const float* __restrict__ ctx,
                                             const ushort* __restrict__ wkvb,
                                             const float* __restrict__ bkv,
                                             ushort* __restrict__ kvb) {
    __shared__ ushort sW[Dc * SWs];          // 25344 B
    const int bn = blockIdx.x, c0 = blockIdx.y * 128;
    const int b = bn / Nc, n = bn % Nc;
    const int tid = threadIdx.x, wave = tid >> 6, lane = tid & 63;
    const int tr = lane & 15, kg = lane >> 4;
    const float* ctxb = ctx + ((size_t)b * Cc * Nc + n) * DEc;

    for (int l = tid; l < Dc * 32; l += 256) {
        int d = l >> 5, e = (l & 31) << 3;
        *reinterpret_cast<short8*>(&sW[d * SWs + e]) =
            *reinterpret_cast<const short8*>(&wkvb[d * DEc + e]);
    }

    const float* crow[2];
    #pragma unroll
    for (int cn = 0; cn < 2; ++cn) {
        int c = c0 + wave * 32 + cn * 16 + tr;
        crow[cn] = ctxb + (size_t)(c < Cc ? c : Cc - 1) * (Nc * DEc);
    }

    f32x4 acc[3][2];
    #pragma unroll
    for (int mf = 0; mf < 3; ++mf)
        #pragma unroll
        for (int cn = 0; cn < 2; ++cn) acc[mf][cn] = (f32x4){0.f, 0.f, 0.f, 0.f};

    __syncthreads();

    #pragma unroll
    for (int ks = 0; ks < 8; ++ks) {
        const int e0 = ks * 32 + kg * 8;
        short8 bfrag[2];
        #pragma unroll
        for (int cn = 0; cn < 2; ++cn) {
            float4 a0 = *reinterpret_cast<const float4*>(crow[cn] + e0);
            float4 a1 = *reinterpret_cast<const float4*>(crow[cn] + e0 + 4);
            bfrag[cn] = pack8(a0, a1);
        }
        short8 afrag[3];
        #pragma unroll
        for (int mf = 0; mf < 3; ++mf)
            afrag[mf] = *reinterpret_cast<const short8*>(&sW[(mf * 16 + tr) * SWs + e0]);
        #pragma unroll
        for (int mf = 0; mf < 3; ++mf)
            #pragma unroll
            for (int cn = 0; cn < 2; ++cn)
                acc[mf][cn] = __builtin_amdgcn_mfma_f32_16x16x32_bf16(afrag[mf], bfrag[cn], acc[mf][cn], 0, 0, 0);
    }

    float4 bias[3];
    #pragma unroll
    for (int mf = 0; mf < 3; ++mf)
        bias[mf] = *reinterpret_cast<const float4*>(bkv + mf * 16 + kg * 4);
    #pragma unroll
    for (int cn = 0; cn < 2; ++cn) {
        int c = c0 + wave * 32 + cn * 16 + tr;
        if (c < Cc) {
            ushort* dst = kvb + ((size_t)bn * Cc + c) * KVP;
            #pragma unroll
            for (int mf = 0; mf < 3; ++mf) {
                ushort4 u;
                u.x = f2b(acc[mf][cn][0] + bias[mf].x);
                u.y = f2b(acc[mf][cn][1] + bias[mf].y);
                u.z = f2b(acc[mf][cn][2] + bias[mf].z);
                u.w = f2b(acc[mf][cn][3] + bias[mf].w);
                *reinterpret_cast<ushort4*>(dst + mf * 16 + kg * 4) = u;
            }
        }
    }
    {
        int row = lane >> 1, half = lane & 1;
        int c = c0 + wave * 32 + row;
        if (c < Cc) {
            short8 z = (short8){0, 0, 0, 0, 0, 0, 0, 0};
            *reinterpret_cast<short8*>(&kvb[((size_t)bn * Cc + c) * KVP + 48 + half * 8]) = z;
        }
    }
}

// ---------------- K2: sp MFMA -> scatter into dense skew rows -> dense dot ----------------
// grid 2880 = 192 bn x 15 t-tiles(8). XCD-grouped: slot=L%8 -> bn in [slot*24, slot*24+24).
constexpr int TT = 8;                 // t-tile
constexpr int MTs = 56;               // M row stride (ushort), 112 B, 16B-aligned
constexpr int MTt = 2696;             // M per-t stride (ushort): 48*56+8 pad -> banks 4t apart
__global__ __launch_bounds__(256) void k2_fused(const float* __restrict__ x,
                                                const ushort* __restrict__ kvb,
                                                float* __restrict__ out) {
    __shared__ ushort sM[TT * MTt];    // 43136 B: M[t][e][d] bf16, skew matrix rows
    __shared__ float  sXf[TT * 52];    // 1664 B
    __shared__ ushort sXb[16 * 72];    // 2304 B (16 rows for MFMA frag; rows 8..15 zero)
    const int L = blockIdx.x;
    const int slot = L & 7, idx = L >> 3;
    const int bn = slot * 24 + idx / 15;
    const int tt = idx % 15;
    const int b = bn / Nc, n = bn % Nc, t0 = tt * TT;
    const int tid = threadIdx.x, wave = tid >> 6, lane = tid & 63;
    const int tr = lane & 15, kg = lane >> 4;

    // zero sXb (all 16 rows) + zero M diagonal
    for (int l = tid; l < 144; l += 256)
        *reinterpret_cast<short8*>(&sXb[l * 8]) = (short8){0,0,0,0,0,0,0,0};
    for (int l = tid; l < TT * Dc; l += 256) {
        int t = l / Dc, d = l - t * Dc;
        sM[t * MTt + d * MTs + d] = 0;
    }
    __syncthreads();
    if (tid < TT * 12) {
        int t = tid / 12, dv = (tid % 12) * 4, tg = t0 + t;
        float4 v = *reinterpret_cast<const float4*>(x + (((size_t)b * Tc + tg) * Nc + n) * Dc + dv);
        *reinterpret_cast<float4*>(&sXf[t * 52 + dv]) = v;
        *reinterpret_cast<ushort4*>(&sXb[t * 72 + dv]) = make_ushort4(f2b(v.x), f2b(v.y), f2b(v.z), f2b(v.w));
    }
    __syncthreads();

    // phase A: sp via MFMA (D: col=tr->c, row=kg*4+r->t), g scattered into M rows
    const short8 af0 = *reinterpret_cast<const short8*>(&sXb[tr * 72 + kg * 8]);
    const short8 af1 = *reinterpret_cast<const short8*>(&sXb[tr * 72 + 32 + kg * 8]);
    const ushort* kvbn = kvb + (size_t)bn * Cc * KVP;
    for (int nf = wave; nf < 71; nf += 4) {
        int c = nf * 16 + tr;
        int ce = c < Cc ? c : Cc - 1;
        short8 b0 = *reinterpret_cast<const short8*>(&kvbn[(size_t)ce * KVP + kg * 8]);
        short8 b1 = *reinterpret_cast<const short8*>(&kvbn[(size_t)ce * KVP + 32 + kg * 8]);
        f32x4 a = (f32x4){0.f, 0.f, 0.f, 0.f};
        a = __builtin_amdgcn_mfma_f32_16x16x32_bf16(af0, b0, a, 0, 0, 0);
        a = __builtin_amdgcn_mfma_f32_16x16x32_bf16(af1, b1, a, 0, 0, 0);
        // pair decode (i > j): i(i-1)/2 <= c < i(i+1)/2
        int i = (int)((1.0f + sqrtf(1.0f + 8.0f * (float)c)) * 0.5f);
        while (i * (i - 1) / 2 > c) --i;
        while ((i + 1) * i / 2 <= c) ++i;
        int j = c - i * (i - 1) / 2;
        const bool cok = (c < Cc);
        #pragma unroll
        for (int r = 0; r < 4; ++r) {
            int t = kg * 4 + r;
            float g = 0.1f - 0.2f * __builtin_amdgcn_rcpf(__expf(2.0f * a[r]) + 1.0f);
            ushort gb = f2b(g);
            if (cok && t < TT) {
                sM[t * MTt + j * MTs + i] = gb;                      // M[e=j][d=i] = +g
                sM[t * MTt + i * MTs + j] = (ushort)(gb ^ 0x8000u);  // M[e=i][d=j] = -g
            }
        }
    }
    __syncthreads();

    // phase B: dense dot. pair idx = e*8 + t; thread does idx=tid and idx=tid+256.
    float xr[48];
    {
        int t = tid & 7;
        #pragma unroll
        for (int v = 0; v < 12; ++v) {
            float4 w = *reinterpret_cast<const float4*>(&sXf[t * 52 + v * 4]);
            xr[v * 4 + 0] = w.x; xr[v * 4 + 1] = w.y;
            xr[v * 4 + 2] = w.z; xr[v * 4 + 3] = w.w;
        }
    }
    #pragma unroll
    for (int pp = 0; pp < 2; ++pp) {
        int pidx = tid + pp * 256;
        if (pidx < TT * Dc) {
            int t = tid & 7, e = pidx >> 3;
            float dx = 0.f;
            #pragma unroll
            for (int v = 0; v < 6; ++v) {
                short8 a8 = *reinterpret_cast<const short8*>(&sM[t * MTt + e * MTs + v * 8]);
                #pragma unroll
                for (int u = 0; u < 8; ++u) {
                    union { unsigned q; float f; } cv;
                    cv.q = ((unsigned)(ushort)a8[u]) << 16;
                    dx = fmaf(xr[v * 8 + u], cv.f, dx);
                }
            }
            int tg = t0 + t;
            out[(((size_t)b * Tc + tg) * Nc + n) * Dc + e] = sXf[t * 52 + e] + dx;
        }
    }
}

extern "C" void kernel_launch(void* const* d_in, const int* in_sizes, int n_in,
                              void* d_out, int out_size, void* d_ws, size_t ws_size,
                              hipStream_t stream) {
    (void)in_sizes; (void)n_in; (void)out_size; (void)ws_size;
    const float* x   = (const float*)d_in[0];
    const float* ctx = (const float*)d_in[1];
    const float* Wkv = (const float*)d_in[2];
    const float* bkv = (const float*)d_in[3];
    float* out   = (float*)d_out;
    ushort* wkvb = (ushort*)d_ws;                          // 24 KB
    ushort* kvb  = (ushort*)((char*)d_ws + 32768);         // 27.7 MB

    k0w<<<dim3(12), dim3(256), 0, stream>>>(Wkv, wkvb);
    k1_kv<<<dim3(BNc, 9), dim3(256), 0, stream>>>(ctx, wkvb, bkv, kvb);
    k2_fused<<<dim3(BNc * 15), dim3(256), 0, stream>>>(x, kvb, out);
}

// Round 9
// 104.805 us; speedup vs baseline: 1.3704x; 1.1769x over previous
//
#include <hip/hip_runtime.h>
#include <hip/hip_bf16.h>

// PosteriorRotationN: B=8,T=120,N=24,D=48,C=1128,DE=256
// k0w: Wkv f32 -> bf16 (24 KB, L2-resident)
// k1 : kv GEMM (bf16 MFMA, swapped operands, bn-grid) -> kvb[bn][c][64]
// k2 : per (bn, 32-t tile): phase A sp MFMA -> g=0.1*tanh(sp) -> G[t][c] bf16 in LDS;
//      phase B per-(t,e) triangular gather dot -> out = x + dx.  4 tiles/bn.

constexpr int Bc = 8, Tc = 120, Nc = 24, Dc = 48, Cc = 1128, DEc = 256;
constexpr int BNc = Bc * Nc;        // 192
constexpr int KVP = 64;             // kv row padded to 64 (zeros at 48..63)

using short8 = __attribute__((ext_vector_type(8))) short;
using f32x4  = __attribute__((ext_vector_type(4))) float;

__device__ __forceinline__ ushort f2b(float f) {
    union { float f; unsigned u; } v; v.f = f;
    unsigned r = (v.u + 0x7fffu + ((v.u >> 16) & 1u)) >> 16;
    return (ushort)r;
}
__device__ __forceinline__ short bcast(float f) {
    return (short)__bfloat16_as_ushort(__float2bfloat16(f));
}
__device__ __forceinline__ short8 pack8(const float4& a, const float4& b) {
    short8 r;
    r[0] = bcast(a.x); r[1] = bcast(a.y); r[2] = bcast(a.z); r[3] = bcast(a.w);
    r[4] = bcast(b.x); r[5] = bcast(b.y); r[6] = bcast(b.z); r[7] = bcast(b.w);
    return r;
}

// ---------------- K0w: Wkv f32 -> bf16 ----------------
__global__ void k0w(const float* __restrict__ Wkv, ushort* __restrict__ wkvb) {
    int i = blockIdx.x * 256 + threadIdx.x;
    float4 w = *reinterpret_cast<const float4*>(Wkv + i * 4);
    ushort4 u;
    u.x = (ushort)bcast(w.x); u.y = (ushort)bcast(w.y);
    u.z = (ushort)bcast(w.z); u.w = (ushort)bcast(w.w);
    *reinterpret_cast<ushort4*>(wkvb + i * 4) = u;
}

// ---------------- K1: kv GEMM, bf16 MFMA, swapped operands (best-measured) ----------------
constexpr int SWs = 264;  // Wkv LDS stride (bf16 elems)
__global__ __launch_bounds__(256) void k1_kv(const float* __restrict__ ctx,
                                             const ushort* __restrict__ wkvb,
                                             const float* __restrict__ bkv,
                                             ushort* __restrict__ kvb) {
    __shared__ ushort sW[Dc * SWs];          // 25344 B
    const int bn = blockIdx.x, c0 = blockIdx.y * 128;
    const int b = bn / Nc, n = bn % Nc;
    const int tid = threadIdx.x, wave = tid >> 6, lane = tid & 63;
    const int tr = lane & 15, kg = lane >> 4;
    const float* ctxb = ctx + ((size_t)b * Cc * Nc + n) * DEc;

    for (int l = tid; l < Dc * 32; l += 256) {
        int d = l >> 5, e = (l & 31) << 3;
        *reinterpret_cast<short8*>(&sW[d * SWs + e]) =
            *reinterpret_cast<const short8*>(&wkvb[d * DEc + e]);
    }

    const float* crow[2];
    #pragma unroll
    for (int cn = 0; cn < 2; ++cn) {
        int c = c0 + wave * 32 + cn * 16 + tr;
        crow[cn] = ctxb + (size_t)(c < Cc ? c : Cc - 1) * (Nc * DEc);
    }

    f32x4 acc[3][2];
    #pragma unroll
    for (int mf = 0; mf < 3; ++mf)
        #pragma unroll
        for (int cn = 0; cn < 2; ++cn) acc[mf][cn] = (f32x4){0.f, 0.f, 0.f, 0.f};

    __syncthreads();

    #pragma unroll
    for (int ks = 0; ks < 8; ++ks) {
        const int e0 = ks * 32 + kg * 8;
        short8 bfrag[2];
        #pragma unroll
        for (int cn = 0; cn < 2; ++cn) {
            float4 a0 = *reinterpret_cast<const float4*>(crow[cn] + e0);
            float4 a1 = *reinterpret_cast<const float4*>(crow[cn] + e0 + 4);
            bfrag[cn] = pack8(a0, a1);
        }
        short8 afrag[3];
        #pragma unroll
        for (int mf = 0; mf < 3; ++mf)
            afrag[mf] = *reinterpret_cast<const short8*>(&sW[(mf * 16 + tr) * SWs + e0]);
        #pragma unroll
        for (int mf = 0; mf < 3; ++mf)
            #pragma unroll
            for (int cn = 0; cn < 2; ++cn)
                acc[mf][cn] = __builtin_amdgcn_mfma_f32_16x16x32_bf16(afrag[mf], bfrag[cn], acc[mf][cn], 0, 0, 0);
    }

    float4 bias[3];
    #pragma unroll
    for (int mf = 0; mf < 3; ++mf)
        bias[mf] = *reinterpret_cast<const float4*>(bkv + mf * 16 + kg * 4);
    #pragma unroll
    for (int cn = 0; cn < 2; ++cn) {
        int c = c0 + wave * 32 + cn * 16 + tr;
        if (c < Cc) {
            ushort* dst = kvb + ((size_t)bn * Cc + c) * KVP;
            #pragma unroll
            for (int mf = 0; mf < 3; ++mf) {
                ushort4 u;
                u.x = f2b(acc[mf][cn][0] + bias[mf].x);
                u.y = f2b(acc[mf][cn][1] + bias[mf].y);
                u.z = f2b(acc[mf][cn][2] + bias[mf].z);
                u.w = f2b(acc[mf][cn][3] + bias[mf].w);
                *reinterpret_cast<ushort4*>(dst + mf * 16 + kg * 4) = u;
            }
        }
    }
    {
        int row = lane >> 1, half = lane & 1;
        int c = c0 + wave * 32 + row;
        if (c < Cc) {
            short8 z = (short8){0, 0, 0, 0, 0, 0, 0, 0};
            *reinterpret_cast<short8*>(&kvb[((size_t)bn * Cc + c) * KVP + 48 + half * 8]) = z;
        }
    }
}

// ---------------- K2: TT=32, G bf16 in LDS, 4 tiles/bn ----------------
// grid 768 = 192 bn x 4 t-tiles(32). XCD-grouped: all tiles of a bn share L%8.
constexpr int TT2 = 32;
constexpr int SG2 = 1140;   // ushort stride; (SG2/2)%8==2 -> t-groups on disjoint bank octets
__global__ __launch_bounds__(256) void k2_fused(const float* __restrict__ x,
                                                const ushort* __restrict__ kvb,
                                                float* __restrict__ out) {
    __shared__ ushort sG[TT2 * SG2];   // 72960 B
    __shared__ float  sXf[TT2 * 52];   // 6656 B   (total 79616 -> 2 blocks/CU)
    const int L = blockIdx.x;
    const int slot = L & 7, idx = L >> 3;
    const int bn = slot * 24 + (idx >> 2);
    const int tt = idx & 3;
    const int b = bn / Nc, n = bn % Nc, t0 = tt * TT2;
    const int tid = threadIdx.x, wave = tid >> 6, lane = tid & 63;
    const int tr = lane & 15, kg = lane >> 4;

    // stage x rows f32 (clamped for the partial last tile)
    for (int l = tid; l < TT2 * 12; l += 256) {
        int t = l / 12, dv = (l % 12) * 4;
        int tg = t0 + t; if (tg > Tc - 1) tg = Tc - 1;
        float4 v = *reinterpret_cast<const float4*>(x + (((size_t)b * Tc + tg) * Nc + n) * Dc + dv);
        *reinterpret_cast<float4*>(&sXf[t * 52 + dv]) = v;
    }

    // A-frags direct from global x (L2-resident), bf16-packed
    short8 af[2][2];
    #pragma unroll
    for (int tf = 0; tf < 2; ++tf) {
        int tg = t0 + tf * 16 + tr; if (tg > Tc - 1) tg = Tc - 1;
        const float* xrow = x + (((size_t)b * Tc + tg) * Nc + n) * Dc;
        float4 a0 = *reinterpret_cast<const float4*>(xrow + kg * 8);
        float4 a1 = *reinterpret_cast<const float4*>(xrow + kg * 8 + 4);
        af[tf][0] = pack8(a0, a1);
        if (kg < 2) {
            float4 c0v = *reinterpret_cast<const float4*>(xrow + 32 + kg * 8);
            float4 c1v = *reinterpret_cast<const float4*>(xrow + 32 + kg * 8 + 4);
            af[tf][1] = pack8(c0v, c1v);
        } else af[tf][1] = (short8){0, 0, 0, 0, 0, 0, 0, 0};
    }

    // phase A: 72 c-frags (18/wave, static), 1-deep kv prefetch, 4 MFMA per iter
    const ushort* kvbn = kvb + (size_t)bn * Cc * KVP;
    short8 b0, b1, p0, p1;
    {
        int c = wave * 16 + tr;
        const ushort* p = kvbn + (size_t)c * KVP + kg * 8;
        b0 = *reinterpret_cast<const short8*>(p);
        b1 = *reinterpret_cast<const short8*>(p + 32);
    }
    #pragma unroll
    for (int u = 0; u < 18; ++u) {
        if (u < 17) {
            int c = (wave + (u + 1) * 4) * 16 + tr; if (c > Cc - 1) c = Cc - 1;
            const ushort* p = kvbn + (size_t)c * KVP + kg * 8;
            p0 = *reinterpret_cast<const short8*>(p);
            p1 = *reinterpret_cast<const short8*>(p + 32);
        }
        f32x4 a0 = (f32x4){0.f, 0.f, 0.f, 0.f};
        f32x4 a1 = (f32x4){0.f, 0.f, 0.f, 0.f};
        a0 = __builtin_amdgcn_mfma_f32_16x16x32_bf16(af[0][0], b0, a0, 0, 0, 0);
        a0 = __builtin_amdgcn_mfma_f32_16x16x32_bf16(af[0][1], b1, a0, 0, 0, 0);
        a1 = __builtin_amdgcn_mfma_f32_16x16x32_bf16(af[1][0], b0, a1, 0, 0, 0);
        a1 = __builtin_amdgcn_mfma_f32_16x16x32_bf16(af[1][1], b1, a1, 0, 0, 0);
        int c = (wave + u * 4) * 16 + tr;
        if (c < Cc) {
            #pragma unroll
            for (int r = 0; r < 4; ++r) {
                float g0 = 0.1f - 0.2f * __builtin_amdgcn_rcpf(__expf(2.0f * a0[r]) + 1.0f);
                float g1 = 0.1f - 0.2f * __builtin_amdgcn_rcpf(__expf(2.0f * a1[r]) + 1.0f);
                sG[(kg * 4 + r) * SG2 + c] = f2b(g0);
                sG[(16 + kg * 4 + r) * SG2 + c] = f2b(g1);
            }
        }
        b0 = p0; b1 = p1;
    }
    __syncthreads();

    // phase B: 6 outputs/thread: t = tid&31, e = (tid>>5) + p*8
    const int t_l = tid & 31;
    const int eb = tid >> 5;
    float xr[48];
    #pragma unroll
    for (int v = 0; v < 12; ++v) {
        float4 w = *reinterpret_cast<const float4*>(&sXf[t_l * 52 + v * 4]);
        xr[v * 4 + 0] = w.x; xr[v * 4 + 1] = w.y;
        xr[v * 4 + 2] = w.z; xr[v * 4 + 3] = w.w;
    }
    float dxa[6]; int ep[6], te[6];
    #pragma unroll
    for (int p = 0; p < 6; ++p) {
        ep[p] = eb + p * 8;
        te[p] = ep[p] * (ep[p] - 1) / 2;
        dxa[p] = 0.f;
    }
    const ushort* grow = &sG[t_l * SG2];
    int td = 0;
    #pragma unroll 8
    for (int d = 0; d < 48; ++d) {
        float xv = xr[d];
        #pragma unroll
        for (int p = 0; p < 6; ++p) {
            bool gt = d > ep[p];
            int c = gt ? (td + ep[p]) : (te[p] + d);
            if (c > Cc - 1) c = Cc - 1;           // only hit when d==e (m=0)
            union { unsigned q; float f; } cv;
            cv.q = ((unsigned)grow[c]) << 16;
            float m = gt ? xv : -xv;
            if (d == ep[p]) m = 0.f;
            dxa[p] = fmaf(m, cv.f, dxa[p]);
        }
        td += d;
    }
    int tg = t0 + t_l;
    if (tg < Tc) {
        #pragma unroll
        for (int p = 0; p < 6; ++p)
            out[(((size_t)b * Tc + tg) * Nc + n) * Dc + ep[p]] = sXf[t_l * 52 + ep[p]] + dxa[p];
    }
}

extern "C" void kernel_launch(void* const* d_in, const int* in_sizes, int n_in,
                              void* d_out, int out_size, void* d_ws, size_t ws_size,
                              hipStream_t stream) {
    (void)in_sizes; (void)n_in; (void)out_size; (void)ws_size;
    const float* x   = (const float*)d_in[0];
    const float* ctx = (const float*)d_in[1];
    const float* Wkv = (const float*)d_in[2];
    const float* bkv = (const float*)d_in[3];
    float* out   = (float*)d_out;
    ushort* wkvb = (ushort*)d_ws;                          // 24 KB
    ushort* kvb  = (ushort*)((char*)d_ws + 32768);         // 27.7 MB

    k0w<<<dim3(12), dim3(256), 0, stream>>>(Wkv, wkvb);
    k1_kv<<<dim3(BNc, 9), dim3(256), 0, stream>>>(ctx, wkvb, bkv, kvb);
    k2_fused<<<dim3(BNc * 4), dim3(256), 0, stream>>>(x, kvb, out);
}